// Round 3
// baseline (251.724 us; speedup 1.0000x reference)
//
#include <hip/hip_runtime.h>
#include <math.h>

typedef __attribute__((ext_vector_type(8))) short bf16x8;
typedef __attribute__((ext_vector_type(8))) unsigned short u16x8;
typedef __attribute__((ext_vector_type(4))) unsigned short u16x4;
typedef __attribute__((ext_vector_type(4))) float f32x4;
typedef unsigned short u16;

__device__ __forceinline__ u16 f2bf(float f) {
  unsigned u = __builtin_bit_cast(unsigned, f);
  return (u16)((u + 0x7FFFu + ((u >> 16) & 1u)) >> 16);
}

__device__ __forceinline__ void gload16(const u16* g, u16* l) {
  __builtin_amdgcn_global_load_lds((const __attribute__((address_space(1))) void*)g,
                                   (__attribute__((address_space(3))) void*)l, 16, 0, 0);
}

__device__ __forceinline__ void sbar() {
  __builtin_amdgcn_sched_barrier(0);
  __builtin_amdgcn_s_barrier();
  __builtin_amdgcn_sched_barrier(0);
}

#define VMWAIT(n) asm volatile("s_waitcnt vmcnt(" #n ")" ::: "memory")

__device__ __forceinline__ float decay_of(float d) {
  return 1e-12f + 0.5f + 0.5f / (1.0f + expf(-d));
}

// ---------------- prep: f32 -> bf16 ----------------
__global__ __launch_bounds__(256) void cvt_bf16_kernel(const float* __restrict__ in,
                                                       u16* __restrict__ out, int n4) {
  int i = blockIdx.x * 256 + threadIdx.x;
  if (i >= n4) return;
  const float4 v = ((const float4*)in)[i];
  u16x4 o = { f2bf(v.x), f2bf(v.y), f2bf(v.z), f2bf(v.w) };
  ((u16x4*)out)[i] = o;
}

// ---------------- prep: relu(cp) transposed to [t][c] bf16 ----------------
__global__ __launch_bounds__(256) void relu_t_kernel(const float* __restrict__ cp,
                                                     u16* __restrict__ x0t) {
  const int cb = blockIdx.x & 31;
  const int tb = blockIdx.x >> 5;
  __shared__ __attribute__((aligned(16))) float tile[64][65];
  const int tid = threadIdx.x;
  const int r0 = tid >> 4, i4 = (tid & 15) * 4;
  #pragma unroll
  for (int rr = 0; rr < 64; rr += 16) {
    const float4 v = *(const float4*)(cp + (size_t)(cb * 64 + r0 + rr) * 4096 + tb * 64 + i4);
    tile[r0 + rr][i4 + 0] = fmaxf(v.x, 0.f);
    tile[r0 + rr][i4 + 1] = fmaxf(v.y, 0.f);
    tile[r0 + rr][i4 + 2] = fmaxf(v.z, 0.f);
    tile[r0 + rr][i4 + 3] = fmaxf(v.w, 0.f);
  }
  __syncthreads();
  #pragma unroll
  for (int it = 0; it < 2; ++it) {
    const int chunk = it * 256 + tid;
    const int i = chunk >> 3, rp = (chunk & 7) * 8;
    u16x8 o;
    #pragma unroll
    for (int q = 0; q < 8; ++q) o[q] = f2bf(tile[rp + q][i]);
    *(u16x8*)(x0t + (size_t)(tb * 64 + i) * 2048 + cb * 64 + rp) = o;
  }
}

// ---------------- IIR blocked scan ----------------
__global__ __launch_bounds__(128) void iir_partial_kernel(const float* __restrict__ x,
                                                          const float* __restrict__ decays,
                                                          float* __restrict__ L) {
  const int tid = threadIdx.x;
  const int cb = blockIdx.x & 15;
  const int ck = blockIdx.x >> 4;
  const int c0 = cb * 128, t0 = ck * 64;
  __shared__ __attribute__((aligned(16))) float xs[128][65];
  const float dd = decay_of(decays[c0 + tid]);
  #pragma unroll
  for (int it = 0; it < 16; ++it) {
    const int idx = it * 128 + tid;
    const int r = idx >> 4, iv = (idx & 15) * 4;
    const float4 v = *(const float4*)(x + (size_t)(c0 + r) * 4096 + t0 + iv);
    xs[r][iv + 0] = v.x; xs[r][iv + 1] = v.y; xs[r][iv + 2] = v.z; xs[r][iv + 3] = v.w;
  }
  __syncthreads();
  float yv = 0.0f;
  #pragma unroll
  for (int i = 0; i < 64; ++i) yv = dd * (xs[tid][i] + yv);
  L[ck * 2048 + c0 + tid] = yv;
}

__global__ __launch_bounds__(128) void iir_carry_kernel(const float* __restrict__ L,
                                                        const float* __restrict__ decays,
                                                        float* __restrict__ Cin) {
  const int c = blockIdx.x * 128 + threadIdx.x;
  const float dd = decay_of(decays[c]);
  float A = dd;
  #pragma unroll
  for (int p = 0; p < 6; ++p) A = A * A;   // dd^64
  float carry = 0.0f;
  for (int j = 0; j < 64; ++j) {
    Cin[j * 2048 + c] = carry;
    carry = L[j * 2048 + c] + A * carry;
  }
}

__global__ __launch_bounds__(128) void iir_apply_kernel(const float* __restrict__ x,
                                                        const float* __restrict__ decays,
                                                        const float* __restrict__ Cin,
                                                        u16* __restrict__ yT) {
  const int tid = threadIdx.x;
  const int cb = blockIdx.x & 15;
  const int ck = blockIdx.x >> 4;
  const int c0 = cb * 128, t0 = ck * 64;
  __shared__ __attribute__((aligned(16))) float xs[128][65];
  __shared__ __attribute__((aligned(16))) u16 ys[64][136];
  const float dd = decay_of(decays[c0 + tid]);
  const float carry = Cin[ck * 2048 + c0 + tid];
  #pragma unroll
  for (int it = 0; it < 16; ++it) {
    const int idx = it * 128 + tid;
    const int r = idx >> 4, iv = (idx & 15) * 4;
    const float4 v = *(const float4*)(x + (size_t)(c0 + r) * 4096 + t0 + iv);
    xs[r][iv + 0] = v.x; xs[r][iv + 1] = v.y; xs[r][iv + 2] = v.z; xs[r][iv + 3] = v.w;
  }
  __syncthreads();
  float yv = carry;
  #pragma unroll
  for (int i = 0; i < 64; ++i) {
    yv = dd * (xs[tid][i] + yv);
    ys[i][tid] = f2bf(yv);
  }
  __syncthreads();
  #pragma unroll
  for (int it = 0; it < 8; ++it) {
    const int chunk = it * 128 + tid;
    const int i = chunk >> 4, cpv = (chunk & 15) * 8;
    u16x8 v = *(const u16x8*)&ys[i][cpv];
    *(u16x8*)(yT + (size_t)(t0 + i) * 2048 + c0 + cpv) = v;
  }
}

// ---------------- GEMM: 256x128 tile, BK=64, triple-buffer, 4-phase ----------------
// C[M][N] = A[M][K] @ Bt[N][K]^T. 512 thr = 8 waves (4M x 2N), per-wave 64x64.
// T2: XOR-swizzled LDS chunks (pre-swizzled global src, swizzled ds_read).
// T3/T4: per-phase stage issues, counted vmcnt(8), raw s_barrier. T5: setprio.
template <int MODE>
__global__ __launch_bounds__(512, 2) void gemm8_kernel(
    const u16* __restrict__ A, const u16* __restrict__ Bt, float* __restrict__ C,
    int N, int K, int nbn,
    const float* __restrict__ orig, const float* __restrict__ gains,
    u16* __restrict__ CbT) {
  __shared__ __attribute__((aligned(16))) u16 Asb[3][256 * 64];  // 96 KB
  __shared__ __attribute__((aligned(16))) u16 Bsb[3][128 * 64];  // 48 KB
  const int tid = threadIdx.x;
  const int l = tid & 63, w = tid >> 6;
  const int wg = (blockIdx.x & 7) * 32 + (blockIdx.x >> 3);   // XCD swizzle (256 wgs)
  const int bm = wg / nbn, bn = wg % nbn;
  const int nt = K >> 6;

  // staging: per wave, A-tile = 32KB = 4 units of 1KB/wave; B-tile = 2 units.
  // lane l covers row (unit*8+w)*8 + (l>>3), 16B chunk (l&7) of that 128B row.
  // swizzle: fetch global chunk ((l&7) ^ (l>>3)) so LDS[r][j] = G[r][j ^ (r&7)].
  const int cs = (l & 7) ^ (l >> 3);
  const int rsub = l >> 3;
  const u16* aS0 = A + (size_t)(bm * 256 + (0 * 8 + w) * 8 + rsub) * K + cs * 8;
  const u16* aS1 = A + (size_t)(bm * 256 + (1 * 8 + w) * 8 + rsub) * K + cs * 8;
  const u16* aS2 = A + (size_t)(bm * 256 + (2 * 8 + w) * 8 + rsub) * K + cs * 8;
  const u16* aS3 = A + (size_t)(bm * 256 + (3 * 8 + w) * 8 + rsub) * K + cs * 8;
  const u16* bS0 = Bt + (size_t)(bn * 128 + (0 * 8 + w) * 8 + rsub) * K + cs * 8;
  const u16* bS1 = Bt + (size_t)(bn * 128 + (1 * 8 + w) * 8 + rsub) * K + cs * 8;
  const int aO0 = (0 * 8 + w) * 512, aO1 = (1 * 8 + w) * 512;
  const int aO2 = (2 * 8 + w) * 512, aO3 = (3 * 8 + w) * 512;
  const int bO0 = (0 * 8 + w) * 512, bO1 = (1 * 8 + w) * 512;

  // prologue: stage tiles 0 and 1 (order matters for vmcnt accounting)
  gload16(aS0, Asb[0] + aO0); gload16(aS1, Asb[0] + aO1);
  gload16(aS2, Asb[0] + aO2); gload16(aS3, Asb[0] + aO3);
  gload16(bS0, Bsb[0] + bO0); gload16(bS1, Bsb[0] + bO1);
  gload16(aS0 + 64, Asb[1] + aO0); gload16(aS1 + 64, Asb[1] + aO1);
  gload16(aS2 + 64, Asb[1] + aO2); gload16(aS3 + 64, Asb[1] + aO3);
  gload16(bS0 + 64, Bsb[1] + bO0); gload16(bS1 + 64, Bsb[1] + bO1);

  f32x4 acc[4][4];
  #pragma unroll
  for (int i = 0; i < 4; ++i)
    #pragma unroll
    for (int j = 0; j < 4; ++j) acc[i][j] = (f32x4){0.f, 0.f, 0.f, 0.f};

  const int wrM = w >> 1, wrN = w & 1;
  const int rA0 = wrM * 64 + (l & 15);          // + mi*16, row stride 64 u16
  const int rB0 = wrN * 64 + (l & 15);          // + ni*16
  const int jk0 = ((l >> 4) + 0) ^ (l & 7);     // swizzled chunk, ksub=0
  const int jk1 = ((l >> 4) + 4) ^ (l & 7);     // swizzled chunk, ksub=1

  bf16x8 af0, af1, af2, af3, b0, b1;

  for (int t = 0; t < nt; ++t) {
    const int cur = t % 3;
    const int stq = t + 2;
    const u16* Ac = Asb[cur];
    const u16* Bc = Bsb[cur];
    u16* Anx = Asb[stq % 3];
    u16* Bnx = Bsb[stq % 3];
    const bool st = stq < nt;
    const long so = (long)stq * 64;

    // ---- phase 0: stage A01(t+2); wait tile t landed; k0, n={0,1} ----
    if (st) { gload16(aS0 + so, Anx + aO0); gload16(aS1 + so, Anx + aO1); }
    if (stq < nt)        { VMWAIT(8); }
    else if (t + 1 < nt) { VMWAIT(6); }
    else                 { VMWAIT(0); }
    sbar();
    af0 = *(const bf16x8*)(Ac + (rA0 + 0)  * 64 + jk0 * 8);
    af1 = *(const bf16x8*)(Ac + (rA0 + 16) * 64 + jk0 * 8);
    af2 = *(const bf16x8*)(Ac + (rA0 + 32) * 64 + jk0 * 8);
    af3 = *(const bf16x8*)(Ac + (rA0 + 48) * 64 + jk0 * 8);
    b0  = *(const bf16x8*)(Bc + (rB0 + 0)  * 64 + jk0 * 8);
    b1  = *(const bf16x8*)(Bc + (rB0 + 16) * 64 + jk0 * 8);
    __builtin_amdgcn_s_setprio(1);
    acc[0][0] = __builtin_amdgcn_mfma_f32_16x16x32_bf16(af0, b0, acc[0][0], 0, 0, 0);
    acc[1][0] = __builtin_amdgcn_mfma_f32_16x16x32_bf16(af1, b0, acc[1][0], 0, 0, 0);
    acc[2][0] = __builtin_amdgcn_mfma_f32_16x16x32_bf16(af2, b0, acc[2][0], 0, 0, 0);
    acc[3][0] = __builtin_amdgcn_mfma_f32_16x16x32_bf16(af3, b0, acc[3][0], 0, 0, 0);
    acc[0][1] = __builtin_amdgcn_mfma_f32_16x16x32_bf16(af0, b1, acc[0][1], 0, 0, 0);
    acc[1][1] = __builtin_amdgcn_mfma_f32_16x16x32_bf16(af1, b1, acc[1][1], 0, 0, 0);
    acc[2][1] = __builtin_amdgcn_mfma_f32_16x16x32_bf16(af2, b1, acc[2][1], 0, 0, 0);
    acc[3][1] = __builtin_amdgcn_mfma_f32_16x16x32_bf16(af3, b1, acc[3][1], 0, 0, 0);
    __builtin_amdgcn_s_setprio(0);
    sbar();

    // ---- phase 1: stage A23(t+2); k0, n={2,3} ----
    if (st) { gload16(aS2 + so, Anx + aO2); gload16(aS3 + so, Anx + aO3); }
    b0 = *(const bf16x8*)(Bc + (rB0 + 32) * 64 + jk0 * 8);
    b1 = *(const bf16x8*)(Bc + (rB0 + 48) * 64 + jk0 * 8);
    __builtin_amdgcn_s_setprio(1);
    acc[0][2] = __builtin_amdgcn_mfma_f32_16x16x32_bf16(af0, b0, acc[0][2], 0, 0, 0);
    acc[1][2] = __builtin_amdgcn_mfma_f32_16x16x32_bf16(af1, b0, acc[1][2], 0, 0, 0);
    acc[2][2] = __builtin_amdgcn_mfma_f32_16x16x32_bf16(af2, b0, acc[2][2], 0, 0, 0);
    acc[3][2] = __builtin_amdgcn_mfma_f32_16x16x32_bf16(af3, b0, acc[3][2], 0, 0, 0);
    acc[0][3] = __builtin_amdgcn_mfma_f32_16x16x32_bf16(af0, b1, acc[0][3], 0, 0, 0);
    acc[1][3] = __builtin_amdgcn_mfma_f32_16x16x32_bf16(af1, b1, acc[1][3], 0, 0, 0);
    acc[2][3] = __builtin_amdgcn_mfma_f32_16x16x32_bf16(af2, b1, acc[2][3], 0, 0, 0);
    acc[3][3] = __builtin_amdgcn_mfma_f32_16x16x32_bf16(af3, b1, acc[3][3], 0, 0, 0);
    __builtin_amdgcn_s_setprio(0);
    sbar();

    // ---- phase 2: stage B01(t+2); k1, n={0,1} ----
    if (st) { gload16(bS0 + so, Bnx + bO0); gload16(bS1 + so, Bnx + bO1); }
    af0 = *(const bf16x8*)(Ac + (rA0 + 0)  * 64 + jk1 * 8);
    af1 = *(const bf16x8*)(Ac + (rA0 + 16) * 64 + jk1 * 8);
    af2 = *(const bf16x8*)(Ac + (rA0 + 32) * 64 + jk1 * 8);
    af3 = *(const bf16x8*)(Ac + (rA0 + 48) * 64 + jk1 * 8);
    b0  = *(const bf16x8*)(Bc + (rB0 + 0)  * 64 + jk1 * 8);
    b1  = *(const bf16x8*)(Bc + (rB0 + 16) * 64 + jk1 * 8);
    __builtin_amdgcn_s_setprio(1);
    acc[0][0] = __builtin_amdgcn_mfma_f32_16x16x32_bf16(af0, b0, acc[0][0], 0, 0, 0);
    acc[1][0] = __builtin_amdgcn_mfma_f32_16x16x32_bf16(af1, b0, acc[1][0], 0, 0, 0);
    acc[2][0] = __builtin_amdgcn_mfma_f32_16x16x32_bf16(af2, b0, acc[2][0], 0, 0, 0);
    acc[3][0] = __builtin_amdgcn_mfma_f32_16x16x32_bf16(af3, b0, acc[3][0], 0, 0, 0);
    acc[0][1] = __builtin_amdgcn_mfma_f32_16x16x32_bf16(af0, b1, acc[0][1], 0, 0, 0);
    acc[1][1] = __builtin_amdgcn_mfma_f32_16x16x32_bf16(af1, b1, acc[1][1], 0, 0, 0);
    acc[2][1] = __builtin_amdgcn_mfma_f32_16x16x32_bf16(af2, b1, acc[2][1], 0, 0, 0);
    acc[3][1] = __builtin_amdgcn_mfma_f32_16x16x32_bf16(af3, b1, acc[3][1], 0, 0, 0);
    __builtin_amdgcn_s_setprio(0);
    sbar();

    // ---- phase 3: k1, n={2,3} ----
    b0 = *(const bf16x8*)(Bc + (rB0 + 32) * 64 + jk1 * 8);
    b1 = *(const bf16x8*)(Bc + (rB0 + 48) * 64 + jk1 * 8);
    __builtin_amdgcn_s_setprio(1);
    acc[0][2] = __builtin_amdgcn_mfma_f32_16x16x32_bf16(af0, b0, acc[0][2], 0, 0, 0);
    acc[1][2] = __builtin_amdgcn_mfma_f32_16x16x32_bf16(af1, b0, acc[1][2], 0, 0, 0);
    acc[2][2] = __builtin_amdgcn_mfma_f32_16x16x32_bf16(af2, b0, acc[2][2], 0, 0, 0);
    acc[3][2] = __builtin_amdgcn_mfma_f32_16x16x32_bf16(af3, b0, acc[3][2], 0, 0, 0);
    acc[0][3] = __builtin_amdgcn_mfma_f32_16x16x32_bf16(af0, b1, acc[0][3], 0, 0, 0);
    acc[1][3] = __builtin_amdgcn_mfma_f32_16x16x32_bf16(af1, b1, acc[1][3], 0, 0, 0);
    acc[2][3] = __builtin_amdgcn_mfma_f32_16x16x32_bf16(af2, b1, acc[2][3], 0, 0, 0);
    acc[3][3] = __builtin_amdgcn_mfma_f32_16x16x32_bf16(af3, b1, acc[3][3], 0, 0, 0);
    __builtin_amdgcn_s_setprio(0);
    sbar();
  }

  // ---------------- epilogue ----------------
  const int rb = bm * 256 + wrM * 64 + ((l >> 4) * 4);
  const int cb = bn * 128 + wrN * 64 + (l & 15);
  #pragma unroll
  for (int mi = 0; mi < 4; ++mi) {
    const int row0 = rb + mi * 16;
    float gv0 = 0.f, gv1 = 0.f, gv2 = 0.f, gv3 = 0.f;
    if (MODE == 1) {
      gv0 = 5.0f / (1.0f + expf(-gains[row0 + 0]));
      gv1 = 5.0f / (1.0f + expf(-gains[row0 + 1]));
      gv2 = 5.0f / (1.0f + expf(-gains[row0 + 2]));
      gv3 = 5.0f / (1.0f + expf(-gains[row0 + 3]));
    }
    #pragma unroll
    for (int ni = 0; ni < 4; ++ni) {
      const int col = cb + ni * 16;
      f32x4 v = acc[mi][ni];
      if (MODE == 1) {
        float cpv[4];
        const float gv[4] = { gv0, gv1, gv2, gv3 };
        #pragma unroll
        for (int j = 0; j < 4; ++j) {
          float t = v[j] + orig[(size_t)(row0 + j) * N + col];
          cpv[j] = tanhf(t * gv[j]);
          C[(size_t)(row0 + j) * N + col] = cpv[j];
        }
        u16x4 o = { f2bf(cpv[0]), f2bf(cpv[1]), f2bf(cpv[2]), f2bf(cpv[3]) };
        *(u16x4*)(CbT + (size_t)col * 2048 + row0) = o;
      } else {
        #pragma unroll
        for (int j = 0; j < 4; ++j)
          C[(size_t)(row0 + j) * N + col] = v[j];
      }
    }
  }
}

extern "C" void kernel_launch(void* const* d_in, const int* in_sizes, int n_in,
                              void* d_out, int out_size, void* d_ws, size_t ws_size,
                              hipStream_t stream) {
  const float* cp     = (const float*)d_in[0];
  const float* w1     = (const float*)d_in[1];
  const float* w2     = (const float*)d_in[2];
  const float* audio  = (const float*)d_in[3];
  const float* decays = (const float*)d_in[4];
  const float* gains  = (const float*)d_in[5];

  float* out0 = (float*)d_out;                   // audio_out: [t][w] flat
  float* out1 = out0 + (size_t)2048 * 4096;      // cp_out: [c][t]

  char* ws = (char*)d_ws;
  u16*   w1b    = (u16*)(ws);                    //  8 MB
  u16*   w2b    = (u16*)(ws + 8388608);          //  8 MB
  u16*   audiob = (u16*)(ws + 16777216);         //  8 MB
  float* orig   = (float*)(ws + 25165824);       // 32 MB
  u16*   yT     = (u16*)(ws + 58720256);         // 16 MB
  u16*   x0t    = (u16*)(ws + 75497472);         // 16 MB
  u16*   cpbT   = x0t;                           // reuse after GEMM1
  float* Lbuf   = (float*)(ws + 75497472);       // overlap (dead between GEMM1/GEMM2)
  float* Cin    = (float*)(ws + 75497472 + 524288);

  cvt_bf16_kernel<<<4096, 256, 0, stream>>>(w1, w1b, 1048576);
  cvt_bf16_kernel<<<4096, 256, 0, stream>>>(w2, w2b, 1048576);
  cvt_bf16_kernel<<<4096, 256, 0, stream>>>(audio, audiob, 1048576);
  relu_t_kernel<<<2048, 256, 0, stream>>>(cp, x0t);

  // x = w1 @ relu(cp) -> orig[2048][4096]   (M=2048 -> 8 bm, N=4096 -> 32 bn)
  gemm8_kernel<0><<<256, 512, 0, stream>>>(w1b, x0t, orig, 4096, 2048, 32,
                                           nullptr, nullptr, nullptr);
  // y = IIR(orig) -> yT[4096][2048] bf16
  iir_partial_kernel<<<1024, 128, 0, stream>>>(orig, decays, Lbuf);
  iir_carry_kernel<<<16, 128, 0, stream>>>(Lbuf, decays, Cin);
  iir_apply_kernel<<<1024, 128, 0, stream>>>(orig, decays, Cin, yT);
  // x2 = w2 @ y + orig; cp_out = tanh(x2*g) -> out1 f32, cpbT[t][c] bf16
  gemm8_kernel<1><<<256, 512, 0, stream>>>(w2b, yT, out1, 4096, 2048, 32,
                                           orig, gains, cpbT);
  // audio_out[t][w] = cpbT @ audiob^T   (M=4096 -> 16 bm, N=2048 -> 16 bn)
  gemm8_kernel<0><<<256, 512, 0, stream>>>(cpbT, audiob, out0, 2048, 2048, 16,
                                           nullptr, nullptr, nullptr);
}